// Round 15
// baseline (224.732 us; speedup 1.0000x reference)
//
#include <hip/hip_runtime.h>
#include <cstdint>

#define NN 100000      // nodes
#define NE 1600000     // edges
#define NG 512         // graphs
#define NP 100032      // NN padded (also mult of 32)
#define VOCAB 10000
#define NBUK 256       // dst-range buckets
#define BSZ 391        // nodes per bucket (256*391 = 100096 >= NN+1)
#define CAP 7680       // max edges per bucket (avg 6250, +18 sigma)
#define EPB 1563       // edges per bucket-block (1024*1563 >= NE)

typedef unsigned short u16;
typedef u16      u16x4  __attribute__((ext_vector_type(4)));
typedef u16      u16x8  __attribute__((ext_vector_type(8)));
typedef __bf16   bf16x8 __attribute__((ext_vector_type(8)));
typedef float    f32x4  __attribute__((ext_vector_type(4)));
typedef float    f32x2  __attribute__((ext_vector_type(2)));

__device__ __forceinline__ u16 f2bf(float f) {  // RNE
    unsigned u = __float_as_uint(f);
    unsigned r = ((u >> 16) & 1u) + 0x7FFFu;
    return (u16)((u + r) >> 16);
}
__device__ __forceinline__ float bf2f(u16 h) {
    return __uint_as_float(((unsigned)h) << 16);
}

// monotone float->uint encoding so unsigned atomicMax == float max
__device__ __forceinline__ unsigned encF(float f) {
    unsigned s = __float_as_uint(f);
    return (s & 0x80000000u) ? ~s : (s | 0x80000000u);
}
__device__ __forceinline__ float decF(unsigned m) {
    unsigned s = (m & 0x80000000u) ? (m ^ 0x80000000u) : ~m;
    return __uint_as_float(s);
}

// ---- gather core v4: 32 rows (4 groups of 8) in flight per batch ----
// sub-group s (lanes 8s..8s+7) loads row csr[b0+u*8+s] (same addr -> L1
// broadcast); all 4 group-loads issue before any unpack. deg<=32 (99.99%)
// needs a single batch -> one exposed latency per node.
template <bool HI>
__device__ __forceinline__ void gather8(const int* __restrict__ csr, int beg, int end,
                                        const u16* __restrict__ table, int lane,
                                        f32x2 acc[4]) {
    const int sub = lane >> 3, g8 = (lane & 7) * 8;
    for (int b0 = beg; b0 < end; b0 += 32) {
        bf16x8 c[4] = {{}, {}, {}, {}};
        #pragma unroll
        for (int u = 0; u < 4; ++u) {
            int idx = b0 + u * 8 + sub;
            if (idx < end) {
                int e = csr[idx];                  // same addr for 8 lanes
                int r = HI ? (e >> 17) : (e & 0x1FFFF);
                c[u] = *(const bf16x8*)(table + (size_t)r * 64 + g8);
            }
        }
        #pragma unroll
        for (int u = 0; u < 4; ++u)
            #pragma unroll
            for (int k = 0; k < 4; ++k) {
                f32x2 w = {(float)c[u][2 * k], (float)c[u][2 * k + 1]};
                acc[k] += w;                       // v_cvt_pk + v_pk_add_f32
            }
    }
}

// per-wave LDS transpose reduce, stride 66 (2-way aliasing only = free).
// Per-wave scratch: no barrier needed (compiler inserts lgkmcnt waits).
__device__ __forceinline__ float reduce_dim(const f32x2 acc[4], float* sT, int lane) {
    const int sub = lane >> 3, g8 = (lane & 7) * 8;
    #pragma unroll
    for (int k = 0; k < 4; ++k)
        *(f32x2*)&sT[sub * 66 + g8 + 2 * k] = acc[k];
    float t = 0.0f;
    #pragma unroll
    for (int sg = 0; sg < 8; ++sg) t += sT[sg * 66 + lane];
    return t;
}

__device__ __forceinline__ void prepW_body(const float* __restrict__ Wa,
                                           const float* __restrict__ Wb,
                                           int mode, u16* __restrict__ Wpk, int idx) {
    int fid = idx >> 6, lane = idx & 63;
    int cT = fid >> 2, ks = fid & 3;
    int quad = lane >> 4, l16 = lane & 15;
    int n = cT * 16 + l16;
    u16x8 v;
    #pragma unroll
    for (int j = 0; j < 8; ++j) {
        int k = ks * 32 + quad * 8 + j;
        float f = (mode == 0) ? (k < 64 ? Wa[k * 128 + n] : Wb[(k - 64) * 128 + n])
                              : (n < 64 ? Wa[k * 64 + n] : Wb[k * 64 + (n - 64)]);
        v[j] = f2bf(f);
    }
    *(u16x8*)(Wpk + idx * 8) = v;
}

// ---- fused: [0,1024) bucket-sort pass | [1024,1649) embB | +8 Wpk1 | +8 Wpk2 | +128 om ----
// bucket entry = dstlocal(9) | src(17)
__global__ __launch_bounds__(256) void k_fused(
        const int* __restrict__ ei, int* __restrict__ gcur,
        unsigned* __restrict__ gbuf,
        const float* __restrict__ emb, u16* __restrict__ embB,
        const float* __restrict__ W1l, const float* __restrict__ W1r,
        u16* __restrict__ Wpk1,
        const float* __restrict__ W2l, const float* __restrict__ W2r,
        u16* __restrict__ Wpk2, unsigned* __restrict__ om) {
    const int bid = blockIdx.x, t = threadIdx.x;
    if (bid >= 1024) {
        if (bid < 1649) {            // embB cast, float4-vectorized
            int i = (bid - 1024) * 1024 + t * 4;   // 625*1024 = 640000 = VOCAB*64
            float4 f = *(const float4*)(emb + i);
            u16x4 o = {f2bf(f.x), f2bf(f.y), f2bf(f.z), f2bf(f.w)};
            *(u16x4*)(embB + i) = o;
        } else if (bid < 1657) {
            prepW_body(W1l, W1r, 0, Wpk1, (bid - 1649) * 256 + t);
        } else if (bid < 1665) {
            prepW_body(W2l, W2r, 1, Wpk2, (bid - 1657) * 256 + t);
        } else {
            om[(bid - 1665) * 256 + t] = 0x007FFFFFu;  // encF(-inf), 128 blocks
        }
        return;
    }
    // ---- bucket pass: single <=1563-edge tile ----
    __shared__ int cnt[NBUK];
    __shared__ int start[NBUK];
    __shared__ int gbase[NBUK];
    __shared__ int wsum[4];
    __shared__ unsigned buf[EPB];
    __shared__ unsigned char bkt[EPB];
    const int e0 = bid * EPB;
    const int tc = min(NE - e0, EPB);   // last block: 1051
    cnt[t] = 0;
    __syncthreads();
    unsigned ent[7];
    unsigned char eb[7];
    u16 rk[7];
    int nm = 0;
    for (int i = t; i < tc; i += 256) {
        int dst = ei[NE + e0 + i];
        int src = ei[e0 + i];
        unsigned b = (unsigned)dst / BSZ;
        unsigned dl = (unsigned)dst - b * BSZ;
        ent[nm] = (dl << 17) | (unsigned)src;
        eb[nm] = (unsigned char)b;
        rk[nm] = (u16)atomicAdd(&cnt[b], 1);
        ++nm;
    }
    __syncthreads();
    // 4-wave shuffle scan of 256 counts + global reservation
    {
        int c = cnt[t];
        int s = c;
        #pragma unroll
        for (int d = 1; d < 64; d <<= 1) {
            int v = __shfl_up(s, d, 64);
            if ((t & 63) >= d) s += v;
        }
        if ((t & 63) == 63) wsum[t >> 6] = s;
        __syncthreads();
        int pre = 0;
        #pragma unroll
        for (int w = 0; w < 4; ++w) pre += (w < (t >> 6)) ? wsum[w] : 0;
        start[t] = pre + s - c;
        gbase[t] = atomicAdd(&gcur[t], c);
    }
    __syncthreads();
    for (int k = 0; k < nm; ++k) {
        int pos = start[eb[k]] + rk[k];
        buf[pos] = ent[k];
        bkt[pos] = eb[k];
    }
    __syncthreads();
    for (int i = t; i < tc; i += 256) {
        unsigned b = bkt[i];
        gbuf[(size_t)b * CAP + gbase[b] + (i - start[b])] = buf[i];
    }
}

// ---- pass 2: per-bucket histogram -> wave scan -> offsets -> fill (1 block/bucket) ----
// csr entry = src | (x[src] << 17)
__global__ __launch_bounds__(512) void k_csr(const unsigned* __restrict__ gbuf,
                                             const int* __restrict__ gcur,
                                             const int* __restrict__ x,
                                             int* __restrict__ off,
                                             int* __restrict__ csr) {
    __shared__ int hist[BSZ];
    __shared__ int curL[BSZ];
    __shared__ int wsum[8];
    __shared__ int sred[8];
    const int b = blockIdx.x, t = threadIdx.x;
    if (t < BSZ) hist[t] = 0;
    __syncthreads();
    const int size = gcur[b];
    const unsigned* gb = gbuf + (size_t)b * CAP;
    for (int i = t; i < size; i += 512)
        atomicAdd(&hist[gb[i] >> 17], 1);
    // bucket global base = sum gcur[0..b)
    {
        int v = (t < 256 && t < b) ? gcur[t] : 0;
        #pragma unroll
        for (int d = 32; d > 0; d >>= 1) v += __shfl_down(v, d, 64);
        if ((t & 63) == 0) sred[t >> 6] = v;
    }
    __syncthreads();
    const int gbase = sred[0] + sred[1] + sred[2] + sred[3];
    int h = (t < BSZ) ? hist[t] : 0;
    int s = h;
    #pragma unroll
    for (int d = 1; d < 64; d <<= 1) {
        int v = __shfl_up(s, d, 64);
        if ((t & 63) >= d) s += v;
    }
    if ((t & 63) == 63) wsum[t >> 6] = s;
    __syncthreads();
    int pre = 0;
    #pragma unroll
    for (int w = 0; w < 7; ++w) pre += (w < (t >> 6)) ? wsum[w] : 0;
    if (t < BSZ) {
        int ex = gbase + pre + s - h;  // exclusive global offset
        curL[t] = ex;
        int g0 = b * BSZ;
        if (g0 + t <= NN) off[g0 + t] = ex;  // covers off[NN]=NE
    }
    __syncthreads();
    for (int i = t; i < size; i += 512) {
        unsigned ent = gb[i];
        int src = (int)(ent & 0x1FFFFu);
        int dl  = (int)(ent >> 17);
        int pos = atomicAdd(&curL[dl], 1);
        csr[pos] = src | (x[src] << 17);
    }
}

// ---- fused gather + GEMM1 + GEMM2: block = 32 nodes; sT aliases sH1 ----
__global__ __launch_bounds__(256, 8) void k_gg(
        const int* __restrict__ off, const int* __restrict__ csr,
        const int* __restrict__ x, const u16* __restrict__ embB,
        const u16* __restrict__ Wpk1, const u16* __restrict__ Wpk2,
        const float* __restrict__ b1,
        u16* __restrict__ P, u16* __restrict__ Q) {
    __shared__ __align__(16) u16 sA1[32][136];  // 272 B row stride (bank pad)
    __shared__ __align__(16) u16 sH1[32][136];  // also transpose scratch pre-stage1
    const int wv = threadIdx.x >> 6, lane = threadIdx.x & 63;
    const int quad = lane >> 4, l16 = lane & 15;
    float* sT = (float*)&sH1[0][0] + wv * 528;  // 4*528*4 = 8448 <= 8704 B
    const int base = blockIdx.x * 32;
    // gather phase: wave wv fills local rows [wv*8, wv*8+8)
    for (int it = 0; it < 8; ++it) {
        int lr = wv * 8 + it;
        int node = base + lr;
        if (node < NN) {
            int beg = off[node], end = off[node + 1];
            f32x2 acc[4] = {{0.f, 0.f}, {0.f, 0.f}, {0.f, 0.f}, {0.f, 0.f}};
            gather8<true>(csr, beg, end, embB, lane, acc);
            float tv = reduce_dim(acc, sT, lane);
            sA1[lr][lane] = f2bf(tv / fmaxf((float)(end - beg), 1.0f));
            sA1[lr][64 + lane] = embB[x[node] * 64 + lane];
        } else {
            sA1[lr][lane] = 0;
            sA1[lr][64 + lane] = 0;
        }
    }
    __syncthreads();
    // stage 1: H1 = relu(sA1 @ W1 + b1) -> sH1
    u16x8 bf1[2][4];
    #pragma unroll
    for (int ct = 0; ct < 2; ++ct)
        #pragma unroll
        for (int ks = 0; ks < 4; ++ks)
            bf1[ct][ks] = *(const u16x8*)(Wpk1 + (((wv * 2 + ct) * 4 + ks) * 64 + lane) * 8);
    f32x4 st1[2][2];
    #pragma unroll
    for (int rt = 0; rt < 2; ++rt) {
        u16x8 a[4];
        #pragma unroll
        for (int ks = 0; ks < 4; ++ks)
            a[ks] = *(const u16x8*)(&sA1[rt * 16 + l16][ks * 32 + quad * 8]);
        #pragma unroll
        for (int ct = 0; ct < 2; ++ct) {
            f32x4 acc = {0.f, 0.f, 0.f, 0.f};
            #pragma unroll
            for (int ks = 0; ks < 4; ++ks)
                acc = __builtin_amdgcn_mfma_f32_16x16x32_bf16(
                    __builtin_bit_cast(bf16x8, a[ks]),
                    __builtin_bit_cast(bf16x8, bf1[ct][ks]), acc, 0, 0, 0);
            st1[rt][ct] = acc;
        }
    }
    __syncthreads();   // all waves done reading sT region before sH1 writes
    #pragma unroll
    for (int rt = 0; rt < 2; ++rt)
        #pragma unroll
        for (int ct = 0; ct < 2; ++ct) {
            int col = wv * 32 + ct * 16 + l16;
            float bias = b1[col];
            int lr = rt * 16 + quad * 4;
            #pragma unroll
            for (int reg = 0; reg < 4; ++reg)
                sH1[lr + reg][col] = f2bf(fmaxf(st1[rt][ct][reg] + bias, 0.f));
        }
    __syncthreads();
    // stage 2: [P|Q] = sH1 @ W2
    u16x8 bf2[2][4];
    #pragma unroll
    for (int ct = 0; ct < 2; ++ct)
        #pragma unroll
        for (int ks = 0; ks < 4; ++ks)
            bf2[ct][ks] = *(const u16x8*)(Wpk2 + (((wv * 2 + ct) * 4 + ks) * 64 + lane) * 8);
    #pragma unroll
    for (int rt = 0; rt < 2; ++rt) {
        u16x8 a[4];
        #pragma unroll
        for (int ks = 0; ks < 4; ++ks)
            a[ks] = *(const u16x8*)(&sH1[rt * 16 + l16][ks * 32 + quad * 8]);
        #pragma unroll
        for (int ct = 0; ct < 2; ++ct) {
            f32x4 acc = {0.f, 0.f, 0.f, 0.f};
            #pragma unroll
            for (int ks = 0; ks < 4; ++ks)
                acc = __builtin_amdgcn_mfma_f32_16x16x32_bf16(
                    __builtin_bit_cast(bf16x8, a[ks]),
                    __builtin_bit_cast(bf16x8, bf2[ct][ks]), acc, 0, 0, 0);
            int col = wv * 32 + ct * 16 + l16;
            int gr = base + rt * 16 + quad * 4;
            u16* dstT = (col < 64) ? P : Q;
            int c = col & 63;
            #pragma unroll
            for (int reg = 0; reg < 4; ++reg)
                dstT[(gr + reg) * 64 + c] = f2bf(acc[reg]);
        }
    }
}

// ---- final: h2 = mean_agg(P) + b2 + Q, segment-max into om ----
// barrier-free: per-wave scratch, direct 64-lane atomicMax per node.
__global__ __launch_bounds__(256, 8) void k_final(const int* __restrict__ off,
                                                  const int* __restrict__ csr,
                                                  const u16* __restrict__ P,
                                                  const u16* __restrict__ Q,
                                                  const float* __restrict__ b2,
                                                  const int* __restrict__ batch,
                                                  unsigned* __restrict__ om) {
    __shared__ float sTT[4][528];
    int wv = threadIdx.x >> 6, lane = threadIdx.x & 63;
    for (int grp = blockIdx.x; grp * 4 < NN; grp += gridDim.x) {
        int node = grp * 4 + wv;  // NN % 4 == 0
        int beg = off[node], end = off[node + 1];
        f32x2 acc[4] = {{0.f, 0.f}, {0.f, 0.f}, {0.f, 0.f}, {0.f, 0.f}};
        gather8<false>(csr, beg, end, P, lane, acc);
        float t = reduce_dim(acc, sTT[wv], lane);
        float r = t / fmaxf((float)(end - beg), 1.0f) + b2[lane]
                + bf2f(Q[node * 64 + lane]);
        atomicMax(&om[batch[node] * 64 + lane], encF(r));
    }
}

__global__ void k_decode(const unsigned* __restrict__ om, float* __restrict__ out) {
    int i = blockIdx.x * blockDim.x + threadIdx.x;
    if (i < NG * 64) out[i] = decF(om[i]);
}

extern "C" void kernel_launch(void* const* d_in, const int* in_sizes, int n_in,
                              void* d_out, int out_size, void* d_ws, size_t ws_size,
                              hipStream_t stream) {
    const int*   x     = (const int*)d_in[0];
    const int*   ei    = (const int*)d_in[1];   // [2, NE] flat: src | dst
    const int*   batch = (const int*)d_in[2];
    // d_in[3] = edge_attr, unused by SAGEConv
    const float* emb   = (const float*)d_in[4];
    const float* W1l   = (const float*)d_in[5];
    const float* b1    = (const float*)d_in[6];
    const float* W1r   = (const float*)d_in[7];
    const float* W2l   = (const float*)d_in[8];
    const float* b2    = (const float*)d_in[9];
    const float* W2r   = (const float*)d_in[10];
    float* out = (float*)d_out;

    // workspace layout (bytes)
    char* p = (char*)d_ws;
    u16* P    = (u16*)p;               p += (size_t)NP * 64 * 2;
    u16* Q    = (u16*)p;               p += (size_t)NP * 64 * 2;
    int* csr  = (int*)p;               p += (size_t)NE * 4;
    unsigned* gbuf = (unsigned*)p;     p += (size_t)NBUK * CAP * 4;
    int* gcur = (int*)p;               p += NBUK * 4;
    int* off  = (int*)p;               p += (size_t)(NN + 1) * 4;
    u16* Wpk1 = (u16*)p;               p += 16384 * 2;
    u16* Wpk2 = (u16*)p;               p += 16384 * 2;
    u16* embB = (u16*)p;               p += (size_t)VOCAB * 64 * 2;
    unsigned* om = (unsigned*)p;

    hipMemsetAsync(gcur, 0, sizeof(int) * NBUK, stream);
    k_fused<<<1793, 256, 0, stream>>>(ei, gcur, gbuf, emb, embB,
                                      W1l, W1r, Wpk1, W2l, W2r, Wpk2, om);
    k_csr<<<NBUK, 512, 0, stream>>>(gbuf, gcur, x, off, csr);
    k_gg<<<NP / 32, 256, 0, stream>>>(off, csr, x, embB, Wpk1, Wpk2, b1, P, Q);
    k_final<<<2048, 256, 0, stream>>>(off, csr, P, Q, b2, batch, om);
    k_decode<<<(NG * 64 + 255) / 256, 256, 0, stream>>>(om, out);
}

// Round 16
// 209.469 us; speedup vs baseline: 1.0729x; 1.0729x over previous
//
#include <hip/hip_runtime.h>
#include <cstdint>

#define NN 100000      // nodes
#define NE 1600000     // edges
#define NG 512         // graphs
#define NP 100032      // NN padded (also mult of 32)
#define VOCAB 10000
#define NBUK 256       // dst-range buckets
#define BSZ 391        // nodes per bucket (256*391 = 100096 >= NN+1)
#define CAP 7680       // max edges per bucket (avg 6250, +18 sigma)
#define EPB 1563       // edges per bucket-block (1024*1563 >= NE)

typedef unsigned short u16;
typedef u16      u16x4  __attribute__((ext_vector_type(4)));
typedef u16      u16x8  __attribute__((ext_vector_type(8)));
typedef __bf16   bf16x8 __attribute__((ext_vector_type(8)));
typedef float    f32x4  __attribute__((ext_vector_type(4)));
typedef float    f32x2  __attribute__((ext_vector_type(2)));

__device__ __forceinline__ u16 f2bf(float f) {  // RNE
    unsigned u = __float_as_uint(f);
    unsigned r = ((u >> 16) & 1u) + 0x7FFFu;
    return (u16)((u + r) >> 16);
}
__device__ __forceinline__ float bf2f(u16 h) {
    return __uint_as_float(((unsigned)h) << 16);
}

// monotone float->uint encoding so unsigned atomicMax == float max
__device__ __forceinline__ unsigned encF(float f) {
    unsigned s = __float_as_uint(f);
    return (s & 0x80000000u) ? ~s : (s | 0x80000000u);
}
__device__ __forceinline__ float decF(unsigned m) {
    unsigned s = (m & 0x80000000u) ? (m ^ 0x80000000u) : ~m;
    return __uint_as_float(s);
}

__device__ __forceinline__ void acc8(f32x2 acc[4], const bf16x8& v) {
    #pragma unroll
    for (int k = 0; k < 4; ++k) {
        f32x2 w = {(float)v[2 * k], (float)v[2 * k + 1]};  // v_cvt_pk_f32_bf16
        acc[k] += w;                                        // v_pk_add_f32
    }
}

// ---- gather v3: 8 rows/step, 2-deep software pipeline (single node) ----
// sub-group s (lanes 8s..8s+7) loads row csr[b0+s] (same addr -> L1 broadcast).
template <bool HI>
__device__ __forceinline__ void gather8(const int* __restrict__ csr, int beg, int end,
                                        const u16* __restrict__ table, int lane,
                                        f32x2 acc[4]) {
    if (beg >= end) return;
    const int sub = lane >> 3, g8 = (lane & 7) * 8;
    auto ld = [&](int b0) -> bf16x8 {
        bf16x8 v = {};
        int idx = b0 + sub;
        if (idx < end) {
            int e = csr[idx];
            int r = HI ? (e >> 17) : (e & 0x1FFFF);
            v = *(const bf16x8*)(table + (size_t)r * 64 + g8);
        }
        return v;
    };
    bf16x8 c0 = ld(beg);
    bf16x8 c1 = ld(beg + 8);
    for (int b0 = beg + 16; b0 < end; b0 += 8) {
        bf16x8 n = ld(b0);
        acc8(acc, c0);
        c0 = c1;
        c1 = n;
    }
    acc8(acc, c0);
    acc8(acc, c1);
}

// ---- pair-gather: two independent nodes per wave -> 2x loads in flight ----
template <bool HI>
__device__ __forceinline__ void gather8_pair(const int* __restrict__ csr,
                                             int bA, int eA, int bB, int eB,
                                             const u16* __restrict__ table, int lane,
                                             f32x2 accA[4], f32x2 accB[4]) {
    const int sub = lane >> 3, g8 = (lane & 7) * 8;
    auto ld = [&](int b0, int end) -> bf16x8 {
        bf16x8 v = {};
        int idx = b0 + sub;
        if (idx < end) {
            int e = csr[idx];                  // same addr for 8 lanes
            int r = HI ? (e >> 17) : (e & 0x1FFFF);
            v = *(const bf16x8*)(table + (size_t)r * 64 + g8);
        }
        return v;
    };
    bf16x8 ca = ld(bA, eA);                    // zeros if empty
    bf16x8 cb = ld(bB, eB);
    int oA = bA + 8, oB = bB + 8;
    while (oA < eA || oB < eB) {
        bf16x8 na = (oA < eA) ? ld(oA, eA) : bf16x8{};
        bf16x8 nb = (oB < eB) ? ld(oB, eB) : bf16x8{};
        acc8(accA, ca);
        acc8(accB, cb);
        ca = na;
        cb = nb;
        oA += 8;
        oB += 8;
    }
    acc8(accA, ca);
    acc8(accB, cb);
}

// per-wave LDS transpose reduce, stride 66 (2-way aliasing only = free)
__device__ __forceinline__ float reduce_dim(const f32x2 acc[4], float* sT, int lane) {
    const int sub = lane >> 3, g8 = (lane & 7) * 8;
    #pragma unroll
    for (int k = 0; k < 4; ++k)
        *(f32x2*)&sT[sub * 66 + g8 + 2 * k] = acc[k];
    float t = 0.0f;
    #pragma unroll
    for (int sg = 0; sg < 8; ++sg) t += sT[sg * 66 + lane];
    return t;
}

__device__ __forceinline__ void prepW_body(const float* __restrict__ Wa,
                                           const float* __restrict__ Wb,
                                           int mode, u16* __restrict__ Wpk, int idx) {
    int fid = idx >> 6, lane = idx & 63;
    int cT = fid >> 2, ks = fid & 3;
    int quad = lane >> 4, l16 = lane & 15;
    int n = cT * 16 + l16;
    u16x8 v;
    #pragma unroll
    for (int j = 0; j < 8; ++j) {
        int k = ks * 32 + quad * 8 + j;
        float f = (mode == 0) ? (k < 64 ? Wa[k * 128 + n] : Wb[(k - 64) * 128 + n])
                              : (n < 64 ? Wa[k * 64 + n] : Wb[k * 64 + (n - 64)]);
        v[j] = f2bf(f);
    }
    *(u16x8*)(Wpk + idx * 8) = v;
}

// ---- fused: [0,1024) bucket-sort pass | [1024,1649) embB | +8 Wpk1 | +8 Wpk2 | +128 om ----
// bucket entry = dstlocal(9) | src(17)
__global__ __launch_bounds__(256) void k_fused(
        const int* __restrict__ ei, int* __restrict__ gcur,
        unsigned* __restrict__ gbuf,
        const float* __restrict__ emb, u16* __restrict__ embB,
        const float* __restrict__ W1l, const float* __restrict__ W1r,
        u16* __restrict__ Wpk1,
        const float* __restrict__ W2l, const float* __restrict__ W2r,
        u16* __restrict__ Wpk2, unsigned* __restrict__ om) {
    const int bid = blockIdx.x, t = threadIdx.x;
    if (bid >= 1024) {
        if (bid < 1649) {            // embB cast, float4-vectorized
            int i = (bid - 1024) * 1024 + t * 4;   // 625*1024 = 640000 = VOCAB*64
            float4 f = *(const float4*)(emb + i);
            u16x4 o = {f2bf(f.x), f2bf(f.y), f2bf(f.z), f2bf(f.w)};
            *(u16x4*)(embB + i) = o;
        } else if (bid < 1657) {
            prepW_body(W1l, W1r, 0, Wpk1, (bid - 1649) * 256 + t);
        } else if (bid < 1665) {
            prepW_body(W2l, W2r, 1, Wpk2, (bid - 1657) * 256 + t);
        } else {
            om[(bid - 1665) * 256 + t] = 0x007FFFFFu;  // encF(-inf), 128 blocks
        }
        return;
    }
    // ---- bucket pass: single <=1563-edge tile ----
    __shared__ int cnt[NBUK];
    __shared__ int start[NBUK];
    __shared__ int gbase[NBUK];
    __shared__ int wsum[4];
    __shared__ unsigned buf[EPB];
    __shared__ unsigned char bkt[EPB];
    const int e0 = bid * EPB;
    const int tc = min(NE - e0, EPB);   // last block: 1051
    cnt[t] = 0;
    __syncthreads();
    unsigned ent[7];
    unsigned char eb[7];
    u16 rk[7];
    int nm = 0;
    for (int i = t; i < tc; i += 256) {
        int dst = ei[NE + e0 + i];
        int src = ei[e0 + i];
        unsigned b = (unsigned)dst / BSZ;
        unsigned dl = (unsigned)dst - b * BSZ;
        ent[nm] = (dl << 17) | (unsigned)src;
        eb[nm] = (unsigned char)b;
        rk[nm] = (u16)atomicAdd(&cnt[b], 1);
        ++nm;
    }
    __syncthreads();
    // 4-wave shuffle scan of 256 counts + global reservation
    {
        int c = cnt[t];
        int s = c;
        #pragma unroll
        for (int d = 1; d < 64; d <<= 1) {
            int v = __shfl_up(s, d, 64);
            if ((t & 63) >= d) s += v;
        }
        if ((t & 63) == 63) wsum[t >> 6] = s;
        __syncthreads();
        int pre = 0;
        #pragma unroll
        for (int w = 0; w < 4; ++w) pre += (w < (t >> 6)) ? wsum[w] : 0;
        start[t] = pre + s - c;
        gbase[t] = atomicAdd(&gcur[t], c);
    }
    __syncthreads();
    for (int k = 0; k < nm; ++k) {
        int pos = start[eb[k]] + rk[k];
        buf[pos] = ent[k];
        bkt[pos] = eb[k];
    }
    __syncthreads();
    for (int i = t; i < tc; i += 256) {
        unsigned b = bkt[i];
        gbuf[(size_t)b * CAP + gbase[b] + (i - start[b])] = buf[i];
    }
}

// ---- pass 2: per-bucket histogram -> wave scan -> offsets -> fill (1 block/bucket) ----
// csr entry = src | (x[src] << 17)
__global__ __launch_bounds__(512) void k_csr(const unsigned* __restrict__ gbuf,
                                             const int* __restrict__ gcur,
                                             const int* __restrict__ x,
                                             int* __restrict__ off,
                                             int* __restrict__ csr) {
    __shared__ int hist[BSZ];
    __shared__ int curL[BSZ];
    __shared__ int wsum[8];
    __shared__ int sred[8];
    const int b = blockIdx.x, t = threadIdx.x;
    if (t < BSZ) hist[t] = 0;
    __syncthreads();
    const int size = gcur[b];
    const unsigned* gb = gbuf + (size_t)b * CAP;
    for (int i = t; i < size; i += 512)
        atomicAdd(&hist[gb[i] >> 17], 1);
    // bucket global base = sum gcur[0..b)
    {
        int v = (t < 256 && t < b) ? gcur[t] : 0;
        #pragma unroll
        for (int d = 32; d > 0; d >>= 1) v += __shfl_down(v, d, 64);
        if ((t & 63) == 0) sred[t >> 6] = v;
    }
    __syncthreads();
    const int gbase = sred[0] + sred[1] + sred[2] + sred[3];
    int h = (t < BSZ) ? hist[t] : 0;
    int s = h;
    #pragma unroll
    for (int d = 1; d < 64; d <<= 1) {
        int v = __shfl_up(s, d, 64);
        if ((t & 63) >= d) s += v;
    }
    if ((t & 63) == 63) wsum[t >> 6] = s;
    __syncthreads();
    int pre = 0;
    #pragma unroll
    for (int w = 0; w < 7; ++w) pre += (w < (t >> 6)) ? wsum[w] : 0;
    if (t < BSZ) {
        int ex = gbase + pre + s - h;  // exclusive global offset
        curL[t] = ex;
        int g0 = b * BSZ;
        if (g0 + t <= NN) off[g0 + t] = ex;  // covers off[NN]=NE
    }
    __syncthreads();
    for (int i = t; i < size; i += 512) {
        unsigned ent = gb[i];
        int src = (int)(ent & 0x1FFFFu);
        int dl  = (int)(ent >> 17);
        int pos = atomicAdd(&curL[dl], 1);
        csr[pos] = src | (x[src] << 17);
    }
}

// ---- fused gather + GEMM1 + GEMM2: block = 32 nodes; sT aliases sH1 ----
__global__ __launch_bounds__(256, 8) void k_gg(
        const int* __restrict__ off, const int* __restrict__ csr,
        const int* __restrict__ x, const u16* __restrict__ embB,
        const u16* __restrict__ Wpk1, const u16* __restrict__ Wpk2,
        const float* __restrict__ b1,
        u16* __restrict__ P, u16* __restrict__ Q) {
    __shared__ __align__(16) u16 sA1[32][136];  // 272 B row stride (bank pad)
    __shared__ __align__(16) u16 sH1[32][136];  // also transpose scratch pre-stage1
    const int wv = threadIdx.x >> 6, lane = threadIdx.x & 63;
    const int quad = lane >> 4, l16 = lane & 15;
    float* sT = (float*)&sH1[0][0] + wv * 528;  // 4*528*4 = 8448 <= 8704 B
    const int base = blockIdx.x * 32;
    // gather phase: wave wv fills local rows [wv*8, wv*8+8)
    for (int it = 0; it < 8; ++it) {
        int lr = wv * 8 + it;
        int node = base + lr;
        if (node < NN) {
            int beg = off[node], end = off[node + 1];
            f32x2 acc[4] = {{0.f, 0.f}, {0.f, 0.f}, {0.f, 0.f}, {0.f, 0.f}};
            gather8<true>(csr, beg, end, embB, lane, acc);
            float tv = reduce_dim(acc, sT, lane);
            sA1[lr][lane] = f2bf(tv / fmaxf((float)(end - beg), 1.0f));
            sA1[lr][64 + lane] = embB[x[node] * 64 + lane];
        } else {
            sA1[lr][lane] = 0;
            sA1[lr][64 + lane] = 0;
        }
    }
    __syncthreads();
    // stage 1: H1 = relu(sA1 @ W1 + b1) -> sH1
    u16x8 bf1[2][4];
    #pragma unroll
    for (int ct = 0; ct < 2; ++ct)
        #pragma unroll
        for (int ks = 0; ks < 4; ++ks)
            bf1[ct][ks] = *(const u16x8*)(Wpk1 + (((wv * 2 + ct) * 4 + ks) * 64 + lane) * 8);
    f32x4 st1[2][2];
    #pragma unroll
    for (int rt = 0; rt < 2; ++rt) {
        u16x8 a[4];
        #pragma unroll
        for (int ks = 0; ks < 4; ++ks)
            a[ks] = *(const u16x8*)(&sA1[rt * 16 + l16][ks * 32 + quad * 8]);
        #pragma unroll
        for (int ct = 0; ct < 2; ++ct) {
            f32x4 acc = {0.f, 0.f, 0.f, 0.f};
            #pragma unroll
            for (int ks = 0; ks < 4; ++ks)
                acc = __builtin_amdgcn_mfma_f32_16x16x32_bf16(
                    __builtin_bit_cast(bf16x8, a[ks]),
                    __builtin_bit_cast(bf16x8, bf1[ct][ks]), acc, 0, 0, 0);
            st1[rt][ct] = acc;
        }
    }
    __syncthreads();   // all waves done reading sT region before sH1 writes
    #pragma unroll
    for (int rt = 0; rt < 2; ++rt)
        #pragma unroll
        for (int ct = 0; ct < 2; ++ct) {
            int col = wv * 32 + ct * 16 + l16;
            float bias = b1[col];
            int lr = rt * 16 + quad * 4;
            #pragma unroll
            for (int reg = 0; reg < 4; ++reg)
                sH1[lr + reg][col] = f2bf(fmaxf(st1[rt][ct][reg] + bias, 0.f));
        }
    __syncthreads();
    // stage 2: [P|Q] = sH1 @ W2
    u16x8 bf2[2][4];
    #pragma unroll
    for (int ct = 0; ct < 2; ++ct)
        #pragma unroll
        for (int ks = 0; ks < 4; ++ks)
            bf2[ct][ks] = *(const u16x8*)(Wpk2 + (((wv * 2 + ct) * 4 + ks) * 64 + lane) * 8);
    #pragma unroll
    for (int rt = 0; rt < 2; ++rt) {
        u16x8 a[4];
        #pragma unroll
        for (int ks = 0; ks < 4; ++ks)
            a[ks] = *(const u16x8*)(&sH1[rt * 16 + l16][ks * 32 + quad * 8]);
        #pragma unroll
        for (int ct = 0; ct < 2; ++ct) {
            f32x4 acc = {0.f, 0.f, 0.f, 0.f};
            #pragma unroll
            for (int ks = 0; ks < 4; ++ks)
                acc = __builtin_amdgcn_mfma_f32_16x16x32_bf16(
                    __builtin_bit_cast(bf16x8, a[ks]),
                    __builtin_bit_cast(bf16x8, bf2[ct][ks]), acc, 0, 0, 0);
            int col = wv * 32 + ct * 16 + l16;
            int gr = base + rt * 16 + quad * 4;
            u16* dstT = (col < 64) ? P : Q;
            int c = col & 63;
            #pragma unroll
            for (int reg = 0; reg < 4; ++reg)
                dstT[(gr + reg) * 64 + c] = f2bf(acc[reg]);
        }
    }
}

// ---- final: h2 = mean_agg(P) + b2 + Q, segment-max into om ----
// wave = 2 nodes (pair-gather, 2x loads in flight); block = 8 nodes,
// leader pre-reduction over 8 consecutive (batch-sorted) nodes.
__global__ __launch_bounds__(256, 8) void k_final(const int* __restrict__ off,
                                                  const int* __restrict__ csr,
                                                  const u16* __restrict__ P,
                                                  const u16* __restrict__ Q,
                                                  const float* __restrict__ b2,
                                                  const int* __restrict__ batch,
                                                  unsigned* __restrict__ om) {
    __shared__ float sTT[4][528];
    __shared__ float sR[8][64];
    __shared__ int sG[8];
    int wv = threadIdx.x >> 6, lane = threadIdx.x & 63;
    for (int grp = blockIdx.x; grp * 8 < NN; grp += gridDim.x) {  // NN % 8 == 0
        int node0 = grp * 8 + wv * 2;
        int node1 = node0 + 1;
        int b0 = off[node0], e0 = off[node0 + 1];
        int b1 = off[node1], e1 = off[node1 + 1];
        f32x2 acc0[4] = {{0.f, 0.f}, {0.f, 0.f}, {0.f, 0.f}, {0.f, 0.f}};
        f32x2 acc1[4] = {{0.f, 0.f}, {0.f, 0.f}, {0.f, 0.f}, {0.f, 0.f}};
        gather8_pair<false>(csr, b0, e0, b1, e1, P, lane, acc0, acc1);
        float t0 = reduce_dim(acc0, sTT[wv], lane);
        float r0 = t0 / fmaxf((float)(e0 - b0), 1.0f) + b2[lane]
                 + bf2f(Q[node0 * 64 + lane]);
        float t1 = reduce_dim(acc1, sTT[wv], lane);
        float r1 = t1 / fmaxf((float)(e1 - b1), 1.0f) + b2[lane]
                 + bf2f(Q[node1 * 64 + lane]);
        sR[wv * 2][lane] = r0;
        sR[wv * 2 + 1][lane] = r1;
        if (lane == 0) {
            sG[wv * 2] = batch[node0];
            sG[wv * 2 + 1] = batch[node1];
        }
        __syncthreads();
        #pragma unroll
        for (int s = 0; s < 2; ++s) {
            int slot = wv * 2 + s;
            int g = sG[slot];
            bool leader = (slot == 0) || (sG[slot - 1] != g);
            if (leader) {
                float m = sR[slot][lane];
                for (int u = slot + 1; u < 8 && sG[u] == g; ++u)
                    m = fmaxf(m, sR[u][lane]);
                atomicMax(&om[g * 64 + lane], encF(m));
            }
        }
        __syncthreads();
    }
}

__global__ void k_decode(const unsigned* __restrict__ om, float* __restrict__ out) {
    int i = blockIdx.x * blockDim.x + threadIdx.x;
    if (i < NG * 64) out[i] = decF(om[i]);
}

extern "C" void kernel_launch(void* const* d_in, const int* in_sizes, int n_in,
                              void* d_out, int out_size, void* d_ws, size_t ws_size,
                              hipStream_t stream) {
    const int*   x     = (const int*)d_in[0];
    const int*   ei    = (const int*)d_in[1];   // [2, NE] flat: src | dst
    const int*   batch = (const int*)d_in[2];
    // d_in[3] = edge_attr, unused by SAGEConv
    const float* emb   = (const float*)d_in[4];
    const float* W1l   = (const float*)d_in[5];
    const float* b1    = (const float*)d_in[6];
    const float* W1r   = (const float*)d_in[7];
    const float* W2l   = (const float*)d_in[8];
    const float* b2    = (const float*)d_in[9];
    const float* W2r   = (const float*)d_in[10];
    float* out = (float*)d_out;

    // workspace layout (bytes)
    char* p = (char*)d_ws;
    u16* P    = (u16*)p;               p += (size_t)NP * 64 * 2;
    u16* Q    = (u16*)p;               p += (size_t)NP * 64 * 2;
    int* csr  = (int*)p;               p += (size_t)NE * 4;
    unsigned* gbuf = (unsigned*)p;     p += (size_t)NBUK * CAP * 4;
    int* gcur = (int*)p;               p += NBUK * 4;
    int* off  = (int*)p;               p += (size_t)(NN + 1) * 4;
    u16* Wpk1 = (u16*)p;               p += 16384 * 2;
    u16* Wpk2 = (u16*)p;               p += 16384 * 2;
    u16* embB = (u16*)p;               p += (size_t)VOCAB * 64 * 2;
    unsigned* om = (unsigned*)p;

    hipMemsetAsync(gcur, 0, sizeof(int) * NBUK, stream);
    k_fused<<<1793, 256, 0, stream>>>(ei, gcur, gbuf, emb, embB,
                                      W1l, W1r, Wpk1, W2l, W2r, Wpk2, om);
    k_csr<<<NBUK, 512, 0, stream>>>(gbuf, gcur, x, off, csr);
    k_gg<<<NP / 32, 256, 0, stream>>>(off, csr, x, embB, Wpk1, Wpk2, b1, P, Q);
    k_final<<<2048, 256, 0, stream>>>(off, csr, P, Q, b2, batch, om);
    k_decode<<<(NG * 64 + 255) / 256, 256, 0, stream>>>(om, out);
}